// Round 4
// baseline (119.953 us; speedup 1.0000x reference)
//
#include <hip/hip_runtime.h>
#include <hip/hip_bf16.h>

// Problem constants (fixed by reference):
//   x[N=8][INC=32][INN=50000] fp32, A[OUTN=8192][MAXD=16] int32,
//   mask[OUTN][MAXD][1] fp32, weight[INC=32][OUTC=32] fp32, bias[OUTC=32][OUTN=8192]
//   out[N=8][OUTC=32][OUTN=8192] fp32
// K1: transpose x -> xt[INN][256] bf16 (row j = n*32+c).  K2: gather+pool+matmul fp32.

#define INN   50000
#define NR    256        // N*INC rows
#define OUTN  8192
#define MAXD  16
#define TO    16         // output nodes per block in K2 (keeps 64B store runs)

typedef float  fx4 __attribute__((ext_vector_type(4)));   // clang-native vec for nt builtins

static __device__ __forceinline__ float bf2f(unsigned short u) {
    return __uint_as_float(((unsigned int)u) << 16);
}

// ---------------- Kernel 1: transpose x[256][50000] -> xt_bf16[50000][256] ----
// 64(i) x 64(r) tile, nontemporal fx4 loads along i, ushort4 stores along r.
// LDS pitch 65: load-scatter and store-gather are <=2-way bank-aliased (free).
__global__ __launch_bounds__(256) void transpose_x(const float* __restrict__ x,
                                                   unsigned short* __restrict__ xt) {
    __shared__ float tile[64 * 65];
    const int t  = threadIdx.x;
    const int i0 = blockIdx.x * 64;   // column (INN) tile base
    const int r0 = blockIdx.y * 64;   // row tile base (always < 256)

    // ---- load: lanes sweep i (coalesced 16B), 16 rows per k-step
    {
        const int i4l = t & 15;        // which float4 within the 64-wide i tile
        const int rl0 = t >> 4;        // row within tile
        const fx4* x4 = (const fx4*)x;
        const int i4base = (i0 >> 2) + i4l;
        const bool iv = (i4base < (INN / 4));   // INN % 4 == 0
        for (int k = 0; k < 4; ++k) {
            const int rl = rl0 + 16 * k;
            fx4 v = iv ? __builtin_nontemporal_load(&x4[(size_t)(r0 + rl) * (INN / 4) + i4base])
                       : (fx4){0.f, 0.f, 0.f, 0.f};
            const int ib = i4l * 4;
            tile[(ib + 0) * 65 + rl] = v.x;
            tile[(ib + 1) * 65 + rl] = v.y;
            tile[(ib + 2) * 65 + rl] = v.z;
            tile[(ib + 3) * 65 + rl] = v.w;
        }
    }
    __syncthreads();
    // ---- store: lanes sweep r (coalesced ushort4 = 8B/lane). Keep these
    // cached (NOT nontemporal) — K2 gathers from xt out of L2/L3.
    {
        const int r4l = t & 15;
        const int il0 = t >> 4;
        for (int k = 0; k < 4; ++k) {
            const int il = il0 + 16 * k;
            const int i  = i0 + il;
            if (i < INN) {
                ushort4 b;
                b.x = __bfloat16_as_ushort(__float2bfloat16(tile[il * 65 + r4l * 4 + 0]));
                b.y = __bfloat16_as_ushort(__float2bfloat16(tile[il * 65 + r4l * 4 + 1]));
                b.z = __bfloat16_as_ushort(__float2bfloat16(tile[il * 65 + r4l * 4 + 2]));
                b.w = __bfloat16_as_ushort(__float2bfloat16(tile[il * 65 + r4l * 4 + 3]));
                *(ushort4*)&xt[(size_t)i * NR + r0 + 4 * r4l] = b;
            }
        }
    }
}

// ---------------- Kernel 2: gather + masked pool + 32x32 matmul + bias ------
// One block = 16 output nodes, 512 threads (8 waves) -> 2 blocks/CU,
// 16 waves/CU for latency hiding on the random-index gather.
__global__ __launch_bounds__(512) void gather_gemm(const unsigned short* __restrict__ xt,
                                                   const int*   __restrict__ A,
                                                   const float* __restrict__ mask,
                                                   const float* __restrict__ W,
                                                   const float* __restrict__ bias,
                                                   float* __restrict__ out) {
    // pooled pitch 260: 16B-aligned rows; every LDS op <=2-way aliased (free).
    __shared__ float pooled[TO * 260];
    __shared__ float Wt[32 * 36];      // Wt[cd][c], pitch 36 (16B aligned rows)
    __shared__ int   Ash[TO * MAXD];
    __shared__ float Msh[TO * MAXD];

    const int t  = threadIdx.x;
    const int o0 = blockIdx.x * TO;

    // stage A, mask (256 entries each), and transposed W (1024 weights)
    if (t < 256) {
        Ash[t] = A[o0 * MAXD + t];
        Msh[t] = mask[o0 * MAXD + t];
    }
    for (int k = 0; k < 2; ++k) {
        const int idx = t + 512 * k;
        const int c = idx >> 5, cd = idx & 31;
        Wt[cd * 36 + c] = W[idx];
    }
    __syncthreads();

    // ---- phase 1: gather bf16 rows of xt (512B = full row per wave-instruction)
    {
        const int j  = t & 63;                 // ushort4 column within row
        const int og = t >> 6;                 // 8 wave-groups, 2 nodes each
        const ushort4* xt4 = (const ushort4*)xt;   // row pitch = 64 ushort4
        for (int m = 0; m < 2; ++m) {
            const int ol = og * 2 + m;
            float4 a = make_float4(0.f, 0.f, 0.f, 0.f);
#pragma unroll
            for (int d = 0; d < MAXD; ++d) {
                const int   idx = Ash[ol * MAXD + d];   // wave-uniform -> broadcast
                const float s   = Msh[ol * MAXD + d];
                const ushort4 u = xt4[(size_t)idx * 64 + j];
                a.x += s * bf2f(u.x);
                a.y += s * bf2f(u.y);
                a.z += s * bf2f(u.z);
                a.w += s * bf2f(u.w);
            }
            *(float4*)&pooled[ol * 260 + 4 * j] = a;
        }
    }
    __syncthreads();

    // ---- phase 2: thread = (team, n, cd); team t covers nodes team*8..team*8+7
    {
        const int team = t >> 8;   // 0..1
        const int n  = (t >> 5) & 7;
        const int cd = t & 31;
        float4 w[8];
#pragma unroll
        for (int cc = 0; cc < 8; ++cc)
            w[cc] = *(const float4*)&Wt[cd * 36 + 4 * cc];

        float res[8];
#pragma unroll
        for (int k = 0; k < 8; ++k) {
            const int ol = team * 8 + k;
            const float4* pr = (const float4*)&pooled[ol * 260 + n * 32];
            float s = 0.f;
#pragma unroll
            for (int cc = 0; cc < 8; ++cc) {
                const float4 p = pr[cc];       // 2 addrs/wave -> LDS broadcast
                s += p.x * w[cc].x + p.y * w[cc].y + p.z * w[cc].z + p.w * w[cc].w;
            }
            res[k] = s;
        }

        // lane writes 32B; the sibling team writes the other 32B of each 64B
        // line from the SAME block -> merges in this CU's L2 before HBM.
        const size_t obase = (size_t)n * (32 * OUTN) + (size_t)cd * OUTN + o0 + team * 8;
        const size_t bbase = (size_t)cd * OUTN + o0 + team * 8;
#pragma unroll
        for (int q = 0; q < 2; ++q) {
            const float4 b = *(const float4*)&bias[bbase + 4 * q];
            fx4 r;
            r.x = res[4 * q + 0] + b.x;
            r.y = res[4 * q + 1] + b.y;
            r.z = res[4 * q + 2] + b.z;
            r.w = res[4 * q + 3] + b.w;
            __builtin_nontemporal_store(r, (fx4*)&out[obase + 4 * q]);
        }
    }
}

extern "C" void kernel_launch(void* const* d_in, const int* in_sizes, int n_in,
                              void* d_out, int out_size, void* d_ws, size_t ws_size,
                              hipStream_t stream) {
    const float* x    = (const float*)d_in[0];
    const int*   A    = (const int*)  d_in[1];
    const float* mask = (const float*)d_in[2];
    const float* W    = (const float*)d_in[3];
    const float* bias = (const float*)d_in[4];
    float* out = (float*)d_out;
    unsigned short* xt = (unsigned short*)d_ws;   // 50000*256*2 = 25.6 MB scratch

    // K1: 782 i-tiles (ceil(50000/64)) x 4 r-tiles
    transpose_x<<<dim3(782, 4), 256, 0, stream>>>(x, xt);
    // K2: 8192/16 = 512 blocks x 512 threads
    gather_gemm<<<OUTN / TO, 512, 0, stream>>>(xt, A, mask, W, bias, out);
}

// Round 5
// 111.303 us; speedup vs baseline: 1.0777x; 1.0777x over previous
//
#include <hip/hip_runtime.h>
#include <hip/hip_bf16.h>

// Problem constants (fixed by reference):
//   x[N=8][INC=32][INN=50000] fp32, A[OUTN=8192][MAXD=16] int32,
//   mask[OUTN][MAXD][1] fp32, weight[INC=32][OUTC=32] fp32, bias[OUTC=32][OUTN=8192]
//   out[N=8][OUTC=32][OUTN=8192] fp32
// K1: transpose x -> xt[INN][256] bf16 (row j = n*32+c).  K2: gather+pool+matmul fp32.
// R5: R2 memory ops exactly (no nontemporal anywhere); K2 at 512 threads so the
//     latency-bound gather phase has 16 waves/CU; phase 2 runs on t<256 with
//     R2's full-64B-per-lane store pattern.

#define INN   50000
#define NR    256        // N*INC rows
#define OUTN  8192
#define MAXD  16
#define TO    16         // output nodes per block in K2

static __device__ __forceinline__ float bf2f(unsigned short u) {
    return __uint_as_float(((unsigned int)u) << 16);
}

// ---------------- Kernel 1: transpose x[256][50000] -> xt_bf16[50000][256] ----
// 64(i) x 64(r) tile, float4 loads along i, ushort4 (bf16x4) stores along r.
// LDS pitch 65: load-scatter and store-gather are <=2-way bank-aliased (free).
__global__ __launch_bounds__(256) void transpose_x(const float* __restrict__ x,
                                                   unsigned short* __restrict__ xt) {
    __shared__ float tile[64 * 65];
    const int t  = threadIdx.x;
    const int i0 = blockIdx.x * 64;   // column (INN) tile base
    const int r0 = blockIdx.y * 64;   // row tile base (always < 256)

    // ---- load: lanes sweep i (coalesced float4), 16 rows per k-step
    {
        const int i4l = t & 15;        // which float4 within the 64-wide i tile
        const int rl0 = t >> 4;        // row within tile
        const float4* x4 = (const float4*)x;
        const int i4base = (i0 >> 2) + i4l;
        const bool iv = (i4base < (INN / 4));   // INN % 4 == 0
        for (int k = 0; k < 4; ++k) {
            const int rl = rl0 + 16 * k;
            float4 v = iv ? x4[(size_t)(r0 + rl) * (INN / 4) + i4base]
                          : make_float4(0.f, 0.f, 0.f, 0.f);
            const int ib = i4l * 4;
            tile[(ib + 0) * 65 + rl] = v.x;
            tile[(ib + 1) * 65 + rl] = v.y;
            tile[(ib + 2) * 65 + rl] = v.z;
            tile[(ib + 3) * 65 + rl] = v.w;
        }
    }
    __syncthreads();
    // ---- store: lanes sweep r (coalesced ushort4 = 8B/lane)
    {
        const int r4l = t & 15;
        const int il0 = t >> 4;
        for (int k = 0; k < 4; ++k) {
            const int il = il0 + 16 * k;
            const int i  = i0 + il;
            if (i < INN) {
                ushort4 b;
                b.x = __bfloat16_as_ushort(__float2bfloat16(tile[il * 65 + r4l * 4 + 0]));
                b.y = __bfloat16_as_ushort(__float2bfloat16(tile[il * 65 + r4l * 4 + 1]));
                b.z = __bfloat16_as_ushort(__float2bfloat16(tile[il * 65 + r4l * 4 + 2]));
                b.w = __bfloat16_as_ushort(__float2bfloat16(tile[il * 65 + r4l * 4 + 3]));
                *(ushort4*)&xt[(size_t)i * NR + r0 + 4 * r4l] = b;
            }
        }
    }
}

// ---------------- Kernel 2: gather + masked pool + 32x32 matmul + bias ------
// One block = 16 output nodes, 512 threads (8 waves) -> 16 waves/CU for
// latency hiding on the random-index gather. Phase 2 on t<256 only (R2 store
// pattern: each lane owns a full 64B output run).
__global__ __launch_bounds__(512) void gather_gemm(const unsigned short* __restrict__ xt,
                                                   const int*   __restrict__ A,
                                                   const float* __restrict__ mask,
                                                   const float* __restrict__ W,
                                                   const float* __restrict__ bias,
                                                   float* __restrict__ out) {
    // pooled pitch 260: 16B-aligned rows; every LDS op <=2-way aliased (free).
    __shared__ float pooled[TO * 260];
    __shared__ float Wt[32 * 36];      // Wt[cd][c], pitch 36 (16B aligned rows)
    __shared__ int   Ash[TO * MAXD];
    __shared__ float Msh[TO * MAXD];

    const int t  = threadIdx.x;
    const int o0 = blockIdx.x * TO;

    // stage A, mask (256 entries each), and transposed W (1024 weights)
    if (t < 256) {
        Ash[t] = A[o0 * MAXD + t];
        Msh[t] = mask[o0 * MAXD + t];
    }
    for (int k = 0; k < 2; ++k) {
        const int idx = t + 512 * k;
        const int c = idx >> 5, cd = idx & 31;
        Wt[cd * 36 + c] = W[idx];
    }
    __syncthreads();

    // ---- phase 1: gather bf16 rows of xt (512B = full row per wave-instruction)
    // 8 wave-groups x 2 nodes each.
    {
        const int j  = t & 63;                 // ushort4 column within row
        const int og = t >> 6;                 // 8 wave-groups
        const ushort4* xt4 = (const ushort4*)xt;   // row pitch = 64 ushort4
        for (int m = 0; m < 2; ++m) {
            const int ol = og * 2 + m;
            float4 a = make_float4(0.f, 0.f, 0.f, 0.f);
#pragma unroll
            for (int d = 0; d < MAXD; ++d) {
                const int   idx = Ash[ol * MAXD + d];   // wave-uniform -> broadcast
                const float s   = Msh[ol * MAXD + d];
                const ushort4 u = xt4[(size_t)idx * 64 + j];
                a.x += s * bf2f(u.x);
                a.y += s * bf2f(u.y);
                a.z += s * bf2f(u.z);
                a.w += s * bf2f(u.w);
            }
            *(float4*)&pooled[ol * 260 + 4 * j] = a;
        }
    }
    __syncthreads();

    // ---- phase 2 (t<256 only): thread = (n, cd). 32-term dot per node,
    // each lane writes a full 64B run of out. Phase 2 is ~1% of the kernel,
    // idling waves 4..7 here is free.
    if (t < 256) {
        const int n  = t >> 5;   // 0..7
        const int cd = t & 31;   // 0..31
        float4 w[8];
#pragma unroll
        for (int cc = 0; cc < 8; ++cc)
            w[cc] = *(const float4*)&Wt[cd * 36 + 4 * cc];

        float res[TO];
#pragma unroll
        for (int ol = 0; ol < TO; ++ol) {
            const float4* pr = (const float4*)&pooled[ol * 260 + n * 32];
            float s = 0.f;
#pragma unroll
            for (int cc = 0; cc < 8; ++cc) {
                const float4 p = pr[cc];       // 2 addrs/wave -> LDS broadcast
                s += p.x * w[cc].x + p.y * w[cc].y + p.z * w[cc].z + p.w * w[cc].w;
            }
            res[ol] = s;
        }

        const size_t obase = (size_t)n * (32 * OUTN) + (size_t)cd * OUTN + o0;
        const size_t bbase = (size_t)cd * OUTN + o0;
#pragma unroll
        for (int q = 0; q < 4; ++q) {
            const float4 b = *(const float4*)&bias[bbase + 4 * q];
            float4 r;
            r.x = res[4 * q + 0] + b.x;
            r.y = res[4 * q + 1] + b.y;
            r.z = res[4 * q + 2] + b.z;
            r.w = res[4 * q + 3] + b.w;
            *(float4*)&out[obase + 4 * q] = r;
        }
    }
}

extern "C" void kernel_launch(void* const* d_in, const int* in_sizes, int n_in,
                              void* d_out, int out_size, void* d_ws, size_t ws_size,
                              hipStream_t stream) {
    const float* x    = (const float*)d_in[0];
    const int*   A    = (const int*)  d_in[1];
    const float* mask = (const float*)d_in[2];
    const float* W    = (const float*)d_in[3];
    const float* bias = (const float*)d_in[4];
    float* out = (float*)d_out;
    unsigned short* xt = (unsigned short*)d_ws;   // 50000*256*2 = 25.6 MB scratch

    // K1: 782 i-tiles (ceil(50000/64)) x 4 r-tiles
    transpose_x<<<dim3(782, 4), 256, 0, stream>>>(x, xt);
    // K2: 8192/16 = 512 blocks x 512 threads
    gather_gemm<<<OUTN / TO, 512, 0, stream>>>(xt, A, mask, W, bias, out);
}